// Round 8
// baseline (117.762 us; speedup 1.0000x reference)
//
#include <hip/hip_runtime.h>
#include <hip/hip_bf16.h>

typedef unsigned short u16;
typedef unsigned int u32;
typedef __bf16 bf16x8 __attribute__((ext_vector_type(8)));
typedef float f32x4 __attribute__((ext_vector_type(4)));
typedef unsigned int u32x4 __attribute__((ext_vector_type(4)));
typedef unsigned int u32x2 __attribute__((ext_vector_type(2)));

#define NN 512
#define LL 40
#define DD 128
#define OO 256
#define KK 9
#define MHCL 34
#define TT 32
#define PSTR 136   // pept LDS row stride (u16)
#define KDSTR 72   // kern_s row stride (u16): 64 d + 8 pad
#define WPADL 64   // padded l-dim in preconverted W

#define PEPT_U16 (LL * PSTR)    // 5440 u16 = 10880 B
#define KS_U16   (32 * KDSTR)   // 2304 u16 = 4608 B per kern scratch buffer

__device__ __forceinline__ u16 f2bf(float x) {
    unsigned int u = __builtin_bit_cast(unsigned int, x);
    u = (u + 0x7FFFu + ((u >> 16) & 1u)) >> 16;
    return (u16)u;
}
__device__ __forceinline__ u32 pk2(float a, float b) {
    __hip_bfloat162 h = __float22bfloat162_rn(make_float2(a, b)); // x = low half
    u32 r;
    __builtin_memcpy(&r, &h, 4);
    return r;
}
__device__ __forceinline__ bf16x8 lds_read8(const u16* p) {
    u32x4 r;
    __builtin_memcpy(&r, __builtin_assume_aligned(p, 16), 16);
    return __builtin_bit_cast(bf16x8, r);
}
__device__ __forceinline__ f32x4 mfma16(bf16x8 a, bf16x8 b, f32x4 c) {
    return __builtin_amdgcn_mfma_f32_16x16x32_bf16(a, b, c, 0, 0, 0);
}

// prologue: W fp32 [O][K][34] -> bf16 zero-padded [O][K][64] in ws
__global__ void w_convert(const float* __restrict__ wgt, u32* __restrict__ wp) {
    int i = blockIdx.x * 256 + threadIdx.x;        // 36864 u32 outputs
    if (i >= OO * KK * (WPADL / 2)) return;
    int o = i / (KK * (WPADL / 2));
    int r = i - o * (KK * (WPADL / 2));
    int k = r >> 5;
    int lp = (r & 31) << 1;
    const float* src = wgt + ((size_t)o * KK + k) * MHCL;
    float a = (lp     < MHCL) ? src[lp]     : 0.f;
    float b = (lp + 1 < MHCL) ? src[lp + 1] : 0.f;
    wp[i] = pk2(a, b);
}

// R8 = R7 (wave-private lockstep-free engine, confirmed -30%) + chain cuts:
// (a) mA fragments loaded DIRECTLY from global mhc (L2-resident) -- deletes
//     mhcT LDS staging and 2 of 3 prologue barriers;
// (b) wave-private kern scratch DOUBLE-BUFFER: stage2(k) reads data written a
//     full iteration earlier, reads issued before stage1(k+1)'s 16 MFMAs ->
//     LDS write->read wait off the critical path. (R4's dbuf null was in the
//     lockstep regime; doesn't transfer.)
// (c) W prefetch depth 2. LDS 47744 B -> 3 blocks/CU (~12 waves ~= R7's 11).
template<bool PRE>
__global__ __launch_bounds__(256, 2)
void iconv_kernel(const float* __restrict__ pept,
                  const float* __restrict__ mhc,
                  const float* __restrict__ wgt,
                  const u16* __restrict__ wp,
                  const float* __restrict__ bias,
                  float* __restrict__ out)
{
    // LDS 47744 B: pept[40][136] | 4 waves x 2 x kern_s[32 o'][72]
    __shared__ __align__(16) u16 s_mem[PEPT_U16 + 8 * KS_U16];

    const int tid  = threadIdx.x;
    const int wave = tid >> 6;
    const int pair = wave >> 1;     // pair handles o-chunks {base, base+1}
    const int dh   = wave & 1;      // d-half owner: d in [dh*64, dh*64+64)
    const int lane = tid & 63;
    const int quad = lane >> 4;
    const int l16  = lane & 15;

    const int n  = blockIdx.x >> 1;     // 2 blocks per sample
    const int oh = blockIdx.x & 1;      // o-half: chunks [oh*4, oh*4+4)

    u16* const s_pept = s_mem;
    u16* const ks0    = s_mem + PEPT_U16 + wave * (2 * KS_U16);  // wave-private
    u16* const ks1    = ks0 + KS_U16;

    auto loadW = [&](int o_base, int k, bf16x8 wF[2][2]) {
        if (PRE) {
            #pragma unroll
            for (int mt = 0; mt < 2; ++mt) {
                const u16* wr = wp + ((size_t)(o_base + mt * 16 + l16) * KK + k) * WPADL;
                u32x4 r0, r1;
                __builtin_memcpy(&r0, __builtin_assume_aligned(wr + quad * 8, 16), 16);
                __builtin_memcpy(&r1, __builtin_assume_aligned(wr + 32 + quad * 8, 16), 16);
                wF[mt][0] = __builtin_bit_cast(bf16x8, r0);
                wF[mt][1] = __builtin_bit_cast(bf16x8, r1);
            }
        } else {
            #pragma unroll
            for (int mt = 0; mt < 2; ++mt) {
                const float* wrow = wgt + ((size_t)(o_base + mt * 16 + l16) * KK + k) * MHCL;
                float w8[8];
                __builtin_memcpy(w8, __builtin_assume_aligned(wrow + quad * 8, 8), 32);
                u16 h0[8];
                #pragma unroll
                for (int j = 0; j < 8; ++j) h0[j] = f2bf(w8[j]);
                __builtin_memcpy(&wF[mt][0], h0, 16);
                u16 h1[8] = {0,0,0,0,0,0,0,0};
                if (quad == 0) { h1[0] = f2bf(wrow[32]); h1[1] = f2bf(wrow[33]); }
                __builtin_memcpy(&wF[mt][1], h1, 16);
            }
        }
    };

    // first W fragments: global latency hides under the (short) prologue
    bf16x8 wB[2][2];
    loadW((oh * 4 + pair * 2) * 32, 0, wB);

    // ---- mA fragments DIRECT from global (no LDS staging, no barrier) ----
    // mA[di][ki] = mhc[l = ki*32 + quad*8 + j][d = dh*64 + di*16 + l16], bf16;
    // l >= MHCL are zero: slice ki=1 has only l=32,33 real (quad==0, j<2).
    bf16x8 mA[4][2];
    {
        const float* mg = mhc + (size_t)n * MHCL * DD;
        #pragma unroll
        for (int di = 0; di < 4; ++di) {
            const int d = dh * 64 + di * 16 + l16;
            u16 h0[8];
            #pragma unroll
            for (int j = 0; j < 8; ++j)
                h0[j] = f2bf(mg[(size_t)(quad * 8 + j) * DD + d]);
            __builtin_memcpy(&mA[di][0], h0, 16);
            u16 h1[8] = {0,0,0,0,0,0,0,0};
            if (quad == 0) {
                h1[0] = f2bf(mg[(size_t)32 * DD + d]);
                h1[1] = f2bf(mg[(size_t)33 * DD + d]);
            }
            __builtin_memcpy(&mA[di][1], h1, 16);
        }
    }

    // ---- pept staging fp32 -> bf16 (single barrier) ----
    {
        const float* pg = pept + (size_t)n * LL * DD;
        #pragma unroll 1
        for (int i = tid; i < (LL * DD) / 4; i += 256) {
            int row = i >> 5, c4 = (i & 31) << 2;
            f32x4 v;
            __builtin_memcpy(&v, __builtin_assume_aligned(pg + row * DD + c4, 16), 16);
            u32x2 h = { pk2(v[0], v[1]), pk2(v[2], v[3]) };
            __builtin_memcpy(__builtin_assume_aligned(&s_pept[row * PSTR + c4], 8), &h, 8);
        }
    }
    __syncthreads();

    // stage1: kern[o'=32][d_local=64] for one k -> given private scratch buffer
    auto stage1 = [&](const bf16x8 wF[2][2], u16* kbw) {
        #pragma unroll
        for (int di = 0; di < 4; ++di) {
            f32x4 c0 = {0.f,0.f,0.f,0.f}, c1 = c0;
            c0 = mfma16(mA[di][0], wF[0][0], c0);   // C[d][o' 0..15]
            c0 = mfma16(mA[di][1], wF[0][1], c0);
            c1 = mfma16(mA[di][0], wF[1][0], c1);   // C[d][o' 16..31]
            c1 = mfma16(mA[di][1], wF[1][1], c1);
            u32x2 p0 = { pk2(fmaxf(c0[0], 0.f), fmaxf(c0[1], 0.f)),
                         pk2(fmaxf(c0[2], 0.f), fmaxf(c0[3], 0.f)) };
            u32x2 p1 = { pk2(fmaxf(c1[0], 0.f), fmaxf(c1[1], 0.f)),
                         pk2(fmaxf(c1[2], 0.f), fmaxf(c1[3], 0.f)) };
            __builtin_memcpy(__builtin_assume_aligned(&kbw[l16 * KDSTR + di * 16 + quad * 4], 8), &p0, 8);
            __builtin_memcpy(__builtin_assume_aligned(&kbw[(16 + l16) * KDSTR + di * 16 + quad * 4], 8), &p1, 8);
        }
    };

    #pragma unroll 1
    for (int oci = 0; oci < 2; ++oci) {
        const int obase = (oh * 4 + pair * 2 + oci) * 32;
        // acc[ti][oj]: out[t = ti*16 + quad*4 + r][o' = oj*16 + l16], partial over this d-half
        f32x4 acc00 = {0.f,0.f,0.f,0.f}, acc01 = acc00, acc10 = acc00, acc11 = acc00;

        stage1(wB, ks0);          // kern(0) -> buf0 (wB = W(obase,0), prefetched)
        loadW(obase, 1, wB);      // W(1) in flight under k=0

        // barrier-free pipelined k-loop: buf[k&1] holds kern(k), written one
        // iteration earlier; reads issued BEFORE stage1(k+1)'s independent MFMAs.
        #pragma unroll
        for (int k = 0; k < KK; ++k) {
            u16* const kr = (k & 1) ? ks1 : ks0;
            u16* const kw = (k & 1) ? ks0 : ks1;
            bf16x8 kbv[2][2], apv[2][2];
            #pragma unroll
            for (int ds = 0; ds < 2; ++ds) {
                kbv[ds][0] = lds_read8(&kr[l16 * KDSTR + ds * 32 + quad * 8]);
                kbv[ds][1] = lds_read8(&kr[(16 + l16) * KDSTR + ds * 32 + quad * 8]);
                apv[ds][0] = lds_read8(&s_pept[(k + l16) * PSTR + dh * 64 + ds * 32 + quad * 8]);
                apv[ds][1] = lds_read8(&s_pept[(k + 16 + l16) * PSTR + dh * 64 + ds * 32 + quad * 8]);
            }
            if (k < KK - 1) stage1(wB, kw);                       // kern(k+1), fills read latency
            if (k < KK - 2) loadW(obase, k + 2, wB);              // 2-deep W prefetch
            else if (k == KK - 2 && oci == 0) loadW(obase + 32, 0, wB); // next oc's k=0
            #pragma unroll
            for (int ds = 0; ds < 2; ++ds) {
                acc00 = mfma16(apv[ds][0], kbv[ds][0], acc00);
                acc01 = mfma16(apv[ds][0], kbv[ds][1], acc01);
                acc10 = mfma16(apv[ds][1], kbv[ds][0], acc10);
                acc11 = mfma16(apv[ds][1], kbv[ds][1], acc11);
            }
        }

        // ---- pair reduction: odd wave parks acc in its buf0; even sums+stores ----
        if (dh == 1) {
            float* ox = (float*)ks0;           // 64 lanes x 16 f32 = 4096 B <= 4608
            const int fb = lane * 16;
            __builtin_memcpy(__builtin_assume_aligned(&ox[fb +  0], 16), &acc00, 16);
            __builtin_memcpy(__builtin_assume_aligned(&ox[fb +  4], 16), &acc01, 16);
            __builtin_memcpy(__builtin_assume_aligned(&ox[fb +  8], 16), &acc10, 16);
            __builtin_memcpy(__builtin_assume_aligned(&ox[fb + 12], 16), &acc11, 16);
        }
        __syncthreads();
        if (dh == 0) {
            const float* px = (const float*)(s_mem + PEPT_U16 + (wave + 1) * (2 * KS_U16));
            const int fb = lane * 16;
            f32x4 q00, q01, q10, q11;
            __builtin_memcpy(&q00, __builtin_assume_aligned(&px[fb +  0], 16), 16);
            __builtin_memcpy(&q01, __builtin_assume_aligned(&px[fb +  4], 16), 16);
            __builtin_memcpy(&q10, __builtin_assume_aligned(&px[fb +  8], 16), 16);
            __builtin_memcpy(&q11, __builtin_assume_aligned(&px[fb + 12], 16), 16);
            const float bv0 = bias[obase + l16];
            const float bv1 = bias[obase + 16 + l16];
            f32x4 r00 = acc00 + q00 + bv0;
            f32x4 r01 = acc01 + q01 + bv1;
            f32x4 r10 = acc10 + q10 + bv0;
            f32x4 r11 = acc11 + q11 + bv1;
            float* ob = out + ((size_t)n * OO + obase) * TT;
            __builtin_memcpy(__builtin_assume_aligned(ob + (size_t)l16 * TT + quad * 4, 16), &r00, 16);
            __builtin_memcpy(__builtin_assume_aligned(ob + (size_t)(16 + l16) * TT + quad * 4, 16), &r01, 16);
            __builtin_memcpy(__builtin_assume_aligned(ob + (size_t)l16 * TT + 16 + quad * 4, 16), &r10, 16);
            __builtin_memcpy(__builtin_assume_aligned(ob + (size_t)(16 + l16) * TT + 16 + quad * 4, 16), &r11, 16);
        }
        __syncthreads();   // exchange reads drained before next oc's stage1 reuses scratch
    }
}

extern "C" void kernel_launch(void* const* d_in, const int* in_sizes, int n_in,
                              void* d_out, int out_size, void* d_ws, size_t ws_size,
                              hipStream_t stream) {
    const float* pept = (const float*)d_in[0];
    const float* mhc  = (const float*)d_in[1];
    const float* wgt  = (const float*)d_in[2];
    const float* bias = (const float*)d_in[3];
    float* out = (float*)d_out;

    const size_t w_bytes = (size_t)OO * KK * WPADL * sizeof(u16); // 294,912
    if (ws_size >= w_bytes) {
        w_convert<<<dim3((OO * KK * (WPADL / 2) + 255) / 256), dim3(256), 0, stream>>>(wgt, (u32*)d_ws);
        iconv_kernel<true><<<dim3(NN * 2), dim3(256), 0, stream>>>(pept, mhc, wgt, (const u16*)d_ws, bias, out);
    } else {
        iconv_kernel<false><<<dim3(NN * 2), dim3(256), 0, stream>>>(pept, mhc, wgt, nullptr, bias, out);
    }
}

// Round 9
// 116.602 us; speedup vs baseline: 1.0099x; 1.0099x over previous
//
#include <hip/hip_runtime.h>
#include <hip/hip_bf16.h>

typedef unsigned short u16;
typedef unsigned int u32;
typedef __bf16 bf16x8 __attribute__((ext_vector_type(8)));
typedef float f32x4 __attribute__((ext_vector_type(4)));
typedef unsigned int u32x4 __attribute__((ext_vector_type(4)));
typedef unsigned int u32x2 __attribute__((ext_vector_type(2)));

#define NN 512
#define LL 40
#define DD 128
#define OO 256
#define KK 9
#define MHCL 34
#define TT 32
#define PSTR 136   // pept LDS row stride (u16)
#define KDSTR 72   // kern_s row stride (u16): 64 d + 8 pad
#define WPADL 64   // padded l-dim in preconverted W

#define PEPT_U16 (LL * PSTR)    // 5440 u16 = 10880 B
#define KS_U16   (32 * KDSTR)   // 2304 u16 = 4608 B per-wave kern scratch

__device__ __forceinline__ u16 f2bf(float x) {
    unsigned int u = __builtin_bit_cast(unsigned int, x);
    u = (u + 0x7FFFu + ((u >> 16) & 1u)) >> 16;
    return (u16)u;
}
__device__ __forceinline__ u32 pk2(float a, float b) {
    __hip_bfloat162 h = __float22bfloat162_rn(make_float2(a, b)); // x = low half
    u32 r;
    __builtin_memcpy(&r, &h, 4);
    return r;
}
__device__ __forceinline__ bf16x8 lds_read8(const u16* p) {
    u32x4 r;
    __builtin_memcpy(&r, __builtin_assume_aligned(p, 16), 16);
    return __builtin_bit_cast(bf16x8, r);
}
__device__ __forceinline__ f32x4 mfma16(bf16x8 a, bf16x8 b, f32x4 c) {
    return __builtin_amdgcn_mfma_f32_16x16x32_bf16(a, b, c, 0, 0, 0);
}

// prologue: W fp32 [O][K][34] -> bf16 zero-padded [O][K][64] in ws
__global__ void w_convert(const float* __restrict__ wgt, u32* __restrict__ wp) {
    int i = blockIdx.x * 256 + threadIdx.x;        // 36864 u32 outputs
    if (i >= OO * KK * (WPADL / 2)) return;
    int o = i / (KK * (WPADL / 2));
    int r = i - o * (KK * (WPADL / 2));
    int k = r >> 5;
    int lp = (r & 31) << 1;
    const float* src = wgt + ((size_t)o * KK + k) * MHCL;
    float a = (lp     < MHCL) ? src[lp]     : 0.f;
    float b = (lp + 1 < MHCL) ? src[lp + 1] : 0.f;
    wp[i] = pk2(a, b);
}

// R9 = R7 engine (single wave-private scratch, barrier-free drift k-loop;
// 56.6us confirmed) + R8's edit (a) direct-global mA (deletes mhcT staging +
// 2 barriers, zero LDS cost) + grid NN*4 with ONE o-chunk per pair.
// R8 post-mortem: dbuf's LDS (48KB) cut occupancy 35->22% and cost +10us --
// in the drift regime co-resident blocks ARE the latency filler (R2's "TLP
// null" was lockstep-regime only). Here LDS stays 29.3KB (5 blocks/CU cap)
// and the grid supplies 8 blocks/CU of shorter blocks for finer packing.
template<bool PRE>
__global__ __launch_bounds__(256, 2)
void iconv_kernel(const float* __restrict__ pept,
                  const float* __restrict__ mhc,
                  const float* __restrict__ wgt,
                  const u16* __restrict__ wp,
                  const float* __restrict__ bias,
                  float* __restrict__ out)
{
    // LDS 29312 B: pept[40][136] | 4 x wave-private kern_s[32 o'][72]
    // (kern_s doubles as the pair's acc-exchange buffer in the epilogue).
    __shared__ __align__(16) u16 s_mem[PEPT_U16 + 4 * KS_U16];

    const int tid  = threadIdx.x;
    const int wave = tid >> 6;
    const int pair = wave >> 1;     // pair index within block (0,1)
    const int dh   = wave & 1;      // d-half owner: d in [dh*64, dh*64+64)
    const int lane = tid & 63;
    const int quad = lane >> 4;
    const int l16  = lane & 15;

    const int n  = blockIdx.x >> 2;     // 4 blocks per sample
    const int oq = blockIdx.x & 3;      // o-quarter: chunks {oq*2, oq*2+1}
    const int obase = (oq * 2 + pair) * 32;   // this pair's single o-chunk

    u16* const s_pept = s_mem;
    u16* const ks     = s_mem + PEPT_U16 + wave * KS_U16;   // wave-private

    auto loadW = [&](int o_base, int k, bf16x8 wF[2][2]) {
        if (PRE) {
            #pragma unroll
            for (int mt = 0; mt < 2; ++mt) {
                const u16* wr = wp + ((size_t)(o_base + mt * 16 + l16) * KK + k) * WPADL;
                u32x4 r0, r1;
                __builtin_memcpy(&r0, __builtin_assume_aligned(wr + quad * 8, 16), 16);
                __builtin_memcpy(&r1, __builtin_assume_aligned(wr + 32 + quad * 8, 16), 16);
                wF[mt][0] = __builtin_bit_cast(bf16x8, r0);
                wF[mt][1] = __builtin_bit_cast(bf16x8, r1);
            }
        } else {
            #pragma unroll
            for (int mt = 0; mt < 2; ++mt) {
                const float* wrow = wgt + ((size_t)(o_base + mt * 16 + l16) * KK + k) * MHCL;
                float w8[8];
                __builtin_memcpy(w8, __builtin_assume_aligned(wrow + quad * 8, 8), 32);
                u16 h0[8];
                #pragma unroll
                for (int j = 0; j < 8; ++j) h0[j] = f2bf(w8[j]);
                __builtin_memcpy(&wF[mt][0], h0, 16);
                u16 h1[8] = {0,0,0,0,0,0,0,0};
                if (quad == 0) { h1[0] = f2bf(wrow[32]); h1[1] = f2bf(wrow[33]); }
                __builtin_memcpy(&wF[mt][1], h1, 16);
            }
        }
    };

    // first W fragments: global latency hides under the (short) prologue
    bf16x8 wB[2][2];
    loadW(obase, 0, wB);

    // ---- mA fragments DIRECT from global (no LDS staging, no barrier) ----
    // mA[di][ki] = mhc[l = ki*32 + quad*8 + j][d = dh*64 + di*16 + l16], bf16;
    // l >= MHCL are zero: slice ki=1 has only l=32,33 real (quad==0, j<2).
    bf16x8 mA[4][2];
    {
        const float* mg = mhc + (size_t)n * MHCL * DD;
        #pragma unroll
        for (int di = 0; di < 4; ++di) {
            const int d = dh * 64 + di * 16 + l16;
            u16 h0[8];
            #pragma unroll
            for (int j = 0; j < 8; ++j)
                h0[j] = f2bf(mg[(size_t)(quad * 8 + j) * DD + d]);
            __builtin_memcpy(&mA[di][0], h0, 16);
            u16 h1[8] = {0,0,0,0,0,0,0,0};
            if (quad == 0) {
                h1[0] = f2bf(mg[(size_t)32 * DD + d]);
                h1[1] = f2bf(mg[(size_t)33 * DD + d]);
            }
            __builtin_memcpy(&mA[di][1], h1, 16);
        }
    }

    // ---- pept staging fp32 -> bf16 (single barrier) ----
    {
        const float* pg = pept + (size_t)n * LL * DD;
        #pragma unroll 1
        for (int i = tid; i < (LL * DD) / 4; i += 256) {
            int row = i >> 5, c4 = (i & 31) << 2;
            f32x4 v;
            __builtin_memcpy(&v, __builtin_assume_aligned(pg + row * DD + c4, 16), 16);
            u32x2 h = { pk2(v[0], v[1]), pk2(v[2], v[3]) };
            __builtin_memcpy(__builtin_assume_aligned(&s_pept[row * PSTR + c4], 8), &h, 8);
        }
    }
    __syncthreads();

    // acc[ti][oj]: out[t = ti*16 + quad*4 + r][o' = oj*16 + l16], partial over this d-half
    f32x4 acc00 = {0.f,0.f,0.f,0.f}, acc01 = acc00, acc10 = acc00, acc11 = acc00;

    // barrier-free k-loop: all LDS deps are same-wave (private scratch)
    #pragma unroll 3
    for (int k = 0; k < KK; ++k) {
        // stage1: kern[o'=32][d_local=64] for this k -> private scratch
        #pragma unroll
        for (int di = 0; di < 4; ++di) {
            f32x4 c0 = {0.f,0.f,0.f,0.f}, c1 = c0;
            c0 = mfma16(mA[di][0], wB[0][0], c0);   // C[d][o' 0..15]
            c0 = mfma16(mA[di][1], wB[0][1], c0);
            c1 = mfma16(mA[di][0], wB[1][0], c1);   // C[d][o' 16..31]
            c1 = mfma16(mA[di][1], wB[1][1], c1);
            u32x2 p0 = { pk2(fmaxf(c0[0], 0.f), fmaxf(c0[1], 0.f)),
                         pk2(fmaxf(c0[2], 0.f), fmaxf(c0[3], 0.f)) };
            u32x2 p1 = { pk2(fmaxf(c1[0], 0.f), fmaxf(c1[1], 0.f)),
                         pk2(fmaxf(c1[2], 0.f), fmaxf(c1[3], 0.f)) };
            __builtin_memcpy(__builtin_assume_aligned(&ks[l16 * KDSTR + di * 16 + quad * 4], 8), &p0, 8);
            __builtin_memcpy(__builtin_assume_aligned(&ks[(16 + l16) * KDSTR + di * 16 + quad * 4], 8), &p1, 8);
        }
        // refill wB (fully consumed by stage1 above); latency covered by stage2
        if (k < KK - 1) loadW(obase, k + 1, wB);
        // stage2: acc += pept[t][d] * kern[d][o'], kdim = 64 in 2 slices
        #pragma unroll
        for (int ds = 0; ds < 2; ++ds) {
            bf16x8 kb0 = lds_read8(&ks[l16 * KDSTR + ds * 32 + quad * 8]);
            bf16x8 kb1 = lds_read8(&ks[(16 + l16) * KDSTR + ds * 32 + quad * 8]);
            bf16x8 ap0 = lds_read8(&s_pept[(k + l16) * PSTR + dh * 64 + ds * 32 + quad * 8]);
            bf16x8 ap1 = lds_read8(&s_pept[(k + 16 + l16) * PSTR + dh * 64 + ds * 32 + quad * 8]);
            acc00 = mfma16(ap0, kb0, acc00);
            acc01 = mfma16(ap0, kb1, acc01);
            acc10 = mfma16(ap1, kb0, acc10);
            acc11 = mfma16(ap1, kb1, acc11);
        }
    }

    // ---- pair reduction: odd wave parks acc in its own scratch; even sums+stores ----
    if (dh == 1) {
        float* ox = (float*)ks;            // 64 lanes x 16 f32 = 4096 B <= 4608
        const int fb = lane * 16;
        __builtin_memcpy(__builtin_assume_aligned(&ox[fb +  0], 16), &acc00, 16);
        __builtin_memcpy(__builtin_assume_aligned(&ox[fb +  4], 16), &acc01, 16);
        __builtin_memcpy(__builtin_assume_aligned(&ox[fb +  8], 16), &acc10, 16);
        __builtin_memcpy(__builtin_assume_aligned(&ox[fb + 12], 16), &acc11, 16);
    }
    __syncthreads();
    if (dh == 0) {
        const float* px = (const float*)(s_mem + PEPT_U16 + (wave + 1) * KS_U16);
        const int fb = lane * 16;
        f32x4 q00, q01, q10, q11;
        __builtin_memcpy(&q00, __builtin_assume_aligned(&px[fb +  0], 16), 16);
        __builtin_memcpy(&q01, __builtin_assume_aligned(&px[fb +  4], 16), 16);
        __builtin_memcpy(&q10, __builtin_assume_aligned(&px[fb +  8], 16), 16);
        __builtin_memcpy(&q11, __builtin_assume_aligned(&px[fb + 12], 16), 16);
        const float bv0 = bias[obase + l16];
        const float bv1 = bias[obase + 16 + l16];
        f32x4 r00 = acc00 + q00 + bv0;
        f32x4 r01 = acc01 + q01 + bv1;
        f32x4 r10 = acc10 + q10 + bv0;
        f32x4 r11 = acc11 + q11 + bv1;
        float* ob = out + ((size_t)n * OO + obase) * TT;
        __builtin_memcpy(__builtin_assume_aligned(ob + (size_t)l16 * TT + quad * 4, 16), &r00, 16);
        __builtin_memcpy(__builtin_assume_aligned(ob + (size_t)(16 + l16) * TT + quad * 4, 16), &r01, 16);
        __builtin_memcpy(__builtin_assume_aligned(ob + (size_t)l16 * TT + 16 + quad * 4, 16), &r10, 16);
        __builtin_memcpy(__builtin_assume_aligned(ob + (size_t)(16 + l16) * TT + 16 + quad * 4, 16), &r11, 16);
    }
}

extern "C" void kernel_launch(void* const* d_in, const int* in_sizes, int n_in,
                              void* d_out, int out_size, void* d_ws, size_t ws_size,
                              hipStream_t stream) {
    const float* pept = (const float*)d_in[0];
    const float* mhc  = (const float*)d_in[1];
    const float* wgt  = (const float*)d_in[2];
    const float* bias = (const float*)d_in[3];
    float* out = (float*)d_out;

    const size_t w_bytes = (size_t)OO * KK * WPADL * sizeof(u16); // 294,912
    if (ws_size >= w_bytes) {
        w_convert<<<dim3((OO * KK * (WPADL / 2) + 255) / 256), dim3(256), 0, stream>>>(wgt, (u32*)d_ws);
        iconv_kernel<true><<<dim3(NN * 4), dim3(256), 0, stream>>>(pept, mhc, wgt, (const u16*)d_ws, bias, out);
    } else {
        iconv_kernel<false><<<dim3(NN * 4), dim3(256), 0, stream>>>(pept, mhc, wgt, nullptr, bias, out);
    }
}